// Round 5
// baseline (368.307 us; speedup 1.0000x reference)
//
#include <hip/hip_runtime.h>
#include <math.h>

#define NN 50000
#define EE 800000
#define RR 2
#define LL 2
#define DD 128
#define GG 64
#define CCLS 8
#define NBUK 196     // buckets of 256 dst nodes: bucket = dst >> 8
#define BCAP 6144    // max raw edges per bucket per relation (mean 4082, sigma 64)
#define BCI2 14080   // merged bucket CSR capacity (r0+r1 jointly padded to %16, +32 tail)
                     // worst: 8704 edges + 512 self + 15*256 pad + 32 ~= 13.1k < 14080

typedef unsigned int uint;
typedef unsigned short ushort;
typedef short bf16x8 __attribute__((ext_vector_type(8)));
typedef float f32x4 __attribute__((ext_vector_type(4)));
typedef float f32x2 __attribute__((ext_vector_type(2)));

// ---------------- workspace layout (bytes) ----------------
#define OFF_H1    ((size_t)0)            // [N][64] uint packed bf16      12,800,000
#define OFF_WBT   ((size_t)12800000)     // [L][R][128][128] bf16            131,072
#define OFF_ISD   ((size_t)12931072)     // [2][N] f32                       400,000
#define OFF_RP    ((size_t)13331072)     // rps[50176] + rpc[50176] i32      401,408
#define OFF_CI    ((size_t)13732480)     // [196][BCI2] i32               11,038,720
#define OFF_ZERO  ((size_t)24771200)     // 34,624
#define OFF_BD    ((size_t)24805824)     // [2][196][BCAP] uint            9,633,792
#define OFF_XW    ((size_t)24805824)     // ALIAS of BD (bdata dead after k_csr):
                                         // [2][N+1][128] fp8             12,800,256
// zero region internal offsets (bytes)
#define ZO_GCUR 0        // [2][196] i32 bucket counters (1568 B, pad 1600)
#define ZO_SUM  1600     // [G][D] f32 (32768 B)
#define ZO_CNT  34368    // [G] i32 (256 B)
#define ZERO_BYTES 34624

static __device__ __forceinline__ ushort f2b(float f) {
  uint u = __float_as_uint(f);
  uint r = (u + 0x7fffu + ((u >> 16) & 1u)) >> 16;
  return (ushort)r;
}
static __device__ __forceinline__ float blo(uint u) { return __uint_as_float(u << 16); }
static __device__ __forceinline__ float bhi(uint u) { return __uint_as_float(u & 0xffff0000u); }

// ---------------- W prep: fp32 W[l][r][k][n] -> bf16 WbfT[l][r][n][k] ----------------
__global__ __launch_bounds__(256) void k_wprep(const float* __restrict__ W,
                                               ushort* __restrict__ WT) {
  int idx = blockIdx.x * 256 + threadIdx.x;  // 65536 total
  int lr = idx >> 14;
  int rem = idx & 16383;
  int n = rem >> 7, k = rem & 127;
  WT[lr * 16384 + n * 128 + k] = f2b(W[lr * 16384 + k * 128 + n]);
}

// ---------------- phase 1: partition edges into dst buckets (coalesced) ----------------
__global__ __launch_bounds__(256) void k_part(const int* __restrict__ EI,
                                              int* __restrict__ gcur,
                                              uint* __restrict__ bdata) {
  __shared__ int hist[256];   // bucket counts -> stage-exclusive offsets
  __shared__ int sbase[256];  // scan scratch
  __shared__ int gbase[256];  // global reservation base per bucket
  __shared__ int lcur[256];
  __shared__ uint stage[4096];
  __shared__ unsigned char bstage[4096];
  const int r = blockIdx.y;
  const int t = threadIdx.x;
  const int e0 = blockIdx.x * 4096;
  const int cnt = min(4096, EE - e0);
  hist[t] = 0;
  lcur[t] = 0;
  __syncthreads();

  int src[16], dst[16];
  bool val[4];
#pragma unroll
  for (int j = 0; j < 4; ++j) {
    int i4 = (j * 256 + t) * 4;
    val[j] = (i4 < cnt);
    if (val[j]) {
      int4 s4 = *(const int4*)(EI + (size_t)r * 2 * EE + e0 + i4);
      int4 d4 = *(const int4*)(EI + (size_t)r * 2 * EE + EE + e0 + i4);
      src[j * 4 + 0] = s4.x; src[j * 4 + 1] = s4.y; src[j * 4 + 2] = s4.z; src[j * 4 + 3] = s4.w;
      dst[j * 4 + 0] = d4.x; dst[j * 4 + 1] = d4.y; dst[j * 4 + 2] = d4.z; dst[j * 4 + 3] = d4.w;
#pragma unroll
      for (int i = 0; i < 4; ++i) atomicAdd(&hist[dst[j * 4 + i] >> 8], 1);
    }
  }
  __syncthreads();
  int hv = hist[t];
  if (t < NBUK && hv > 0)
    gbase[t] = atomicAdd(&gcur[r * NBUK + t], hv);
  else
    gbase[t] = 0;
  sbase[t] = hv;
  __syncthreads();
  for (int off = 1; off < 256; off <<= 1) {
    int u = (t >= off) ? sbase[t - off] : 0;
    __syncthreads();
    sbase[t] += u;
    __syncthreads();
  }
  int incl = sbase[t];
  hist[t] = incl - hv;  // exclusive stage offset
  __syncthreads();
#pragma unroll
  for (int j = 0; j < 4; ++j) {
    if (val[j]) {
#pragma unroll
      for (int i = 0; i < 4; ++i) {
        int d = dst[j * 4 + i];
        int b = d >> 8;
        int p = atomicAdd(&lcur[b], 1);
        int pos = hist[b] + p;
        stage[pos] = ((uint)src[j * 4 + i] << 8) | (uint)(d & 255);
        bstage[pos] = (unsigned char)b;
      }
    }
  }
  __syncthreads();
  for (int s = t; s < cnt; s += 256) {
    int b = (int)bstage[s];
    bdata[(size_t)(r * NBUK + b) * BCAP + gbase[b] + (s - hist[b])] = stage[s];
  }
}

// ---------------- phase 2: merged per-node CSR, JOINTLY padded to %16 ----------------
// Per node: [r0 edges..., self(node), r1 edges+(NN+1)..., self(NN+1+node), pads(NN)]
// padded to a multiple of 16 across BOTH relations. end0 = deg0+1 marks the r0/r1
// boundary slot; k_agg selects di0/di1 per slot. Row NN of the fp8 table is zero.
__global__ __launch_bounds__(256) void k_csr(const uint* __restrict__ bdata,
                                             const int* __restrict__ gcur,
                                             float* __restrict__ isd,
                                             int* __restrict__ rps,
                                             int* __restrict__ rpc,
                                             int* __restrict__ ci) {
  __shared__ int lcnt0[256], lcnt1[256], lrp[256], lex[256], lend0[256];
  __shared__ int lcurA[256], lcurB[256];
  __shared__ int cstage[BCI2];   // 56,320 B (+7 KB arrays = 63.3 KB, under 64 KB)
  __shared__ int shtot;
  const int b = blockIdx.x;
  const int t = threadIdx.x;
  const int cnt0 = gcur[b];
  const int cnt1 = gcur[NBUK + b];
  const uint* bd0 = bdata + (size_t)b * BCAP;
  const uint* bd1 = bdata + (size_t)(NBUK + b) * BCAP;
  lcnt0[t] = 0; lcnt1[t] = 0; lcurA[t] = 0; lcurB[t] = 0;
  __syncthreads();
  for (int s = t; s < cnt0; s += 256) atomicAdd(&lcnt0[bd0[s] & 255u], 1);
  for (int s = t; s < cnt1; s += 256) atomicAdd(&lcnt1[bd1[s] & 255u], 1);
  __syncthreads();
  const int deg0 = lcnt0[t];
  const int deg1 = lcnt1[t];
  const int node = b * 256 + t;
  const int valid = (node < NN) ? 1 : 0;
  const int nreal = deg0 + deg1 + 2;                // + both selfs
  const int ng = valid ? ((nreal + 15) >> 4) : 0;   // joint pad to %16
  const int sz = ng << 4;
  const int end0 = deg0 + 1;
  lrp[t] = sz;
  __syncthreads();
  for (int off = 1; off < 256; off <<= 1) {
    int u = (t >= off) ? lrp[t - off] : 0;
    __syncthreads();
    lrp[t] += u;
    __syncthreads();
  }
  const int incl = lrp[t];
  if (t == 255) shtot = incl;
  const int ex = incl - sz;
  lex[t] = ex;
  lend0[t] = end0;
  __syncthreads();   // publish lex / lend0 / shtot
  const int btot = shtot;
  if (t < 32) cstage[btot + t] = NN;   // tail pads for k_agg index over-read
  rps[node] = b * BCI2 + ex;           // written for ALL slots
  rpc[node] = valid ? (ng | (end0 << 16)) : 0;
  if (valid) {
    isd[node] = rsqrtf((float)(deg0 + 1));
    isd[NN + node] = rsqrtf((float)(deg1 + 1));
    cstage[ex + deg0] = node;                         // r0 self at slot deg0
    cstage[ex + end0 + deg1] = (NN + 1) + node;       // r1 self
    for (int p = end0 + deg1 + 1; p < sz; ++p) cstage[ex + p] = NN;  // zero-row pads
  }
  // scatter (disjoint positions vs pads/selfs; lex/lend0 published above)
  for (int s = t; s < cnt0; s += 256) {
    uint pr = bd0[s];
    int j = (int)(pr & 255u);
    int p = atomicAdd(&lcurA[j], 1);
    cstage[lex[j] + p] = (int)(pr >> 8);
  }
  for (int s = t; s < cnt1; s += 256) {
    uint pr = bd1[s];
    int j = (int)(pr & 255u);
    int p = atomicAdd(&lcurB[j], 1);
    cstage[lex[j] + lend0[j] + p] = (int)(pr >> 8) + (NN + 1);
  }
  __syncthreads();
  const int on = btot + 32;
  int* co = ci + (size_t)b * BCI2;
  for (int s = t; s < on; s += 256) co[s] = cstage[s];
}

// ---------------- MFMA GEMM: xw'[r][m][:] = (X[m][:] @ W[r]) * isd[r][m], fp8 out ----------------
#define AL_S 72    // 64+8 bf16 row stride
#define WT_S 136   // 128+8 bf16 row stride
template <int IN_BF16>
__global__ __launch_bounds__(256) void k_gemm(const void* __restrict__ Xv,
                                              const ushort* __restrict__ WTg,
                                              const float* __restrict__ isd,
                                              uint* __restrict__ Y) {
  __shared__ ushort WTl[128 * WT_S];
  __shared__ ushort Al[128 * AL_S];
  const int r = blockIdx.y;
  const int m0b = blockIdx.x * 128;
  const int t = threadIdx.x;
  const int w = t >> 6, L = t & 63, q = L >> 4, ln = L & 15;
  uint* Yr = Y + (size_t)r * (NN + 1) * 32;   // fp8 row = 32 uints, +1 zero row
  const ushort* WTr = WTg + (size_t)r * 16384;

#pragma unroll
  for (int i = 0; i < 8; ++i) {
    int g = t + i * 256;
    int n = g >> 4, k0 = (g & 15) * 8;
    *(uint4*)(&WTl[n * WT_S + k0]) = *(const uint4*)(WTr + n * 128 + k0);
  }

  f32x4 acc[2][8];
#pragma unroll
  for (int mt = 0; mt < 2; ++mt)
#pragma unroll
    for (int nt = 0; nt < 8; ++nt) {
      acc[mt][nt][0] = 0.f; acc[mt][nt][1] = 0.f;
      acc[mt][nt][2] = 0.f; acc[mt][nt][3] = 0.f;
    }

  for (int hh = 0; hh < 2; ++hh) {
    __syncthreads();
    {
      int row = t >> 1, ch = t & 1;
      int gm = m0b + row;
      ushort* dst = &Al[row * AL_S + ch * 32];
      if (gm < NN) {
        if (IN_BF16) {
          const uint4* xp = (const uint4*)((const ushort*)Xv + (size_t)gm * 128 + hh * 64 + ch * 32);
#pragma unroll
          for (int j = 0; j < 4; ++j) ((uint4*)dst)[j] = xp[j];
        } else {
          const float4* xp = (const float4*)((const float*)Xv + (size_t)gm * 128 + hh * 64 + ch * 32);
          ushort tmp[32];
#pragma unroll
          for (int j = 0; j < 8; ++j) {
            float4 v = xp[j];
            tmp[j * 4 + 0] = f2b(v.x); tmp[j * 4 + 1] = f2b(v.y);
            tmp[j * 4 + 2] = f2b(v.z); tmp[j * 4 + 3] = f2b(v.w);
          }
#pragma unroll
          for (int j = 0; j < 4; ++j) ((uint4*)dst)[j] = ((uint4*)tmp)[j];
        }
      } else {
        uint4 z = make_uint4(0, 0, 0, 0);
#pragma unroll
        for (int j = 0; j < 4; ++j) ((uint4*)dst)[j] = z;
      }
    }
    __syncthreads();
#pragma unroll
    for (int kk = 0; kk < 2; ++kk) {
      bf16x8 b0 = *(const bf16x8*)(&Al[(w * 32 + ln) * AL_S + kk * 32 + q * 8]);
      bf16x8 b1 = *(const bf16x8*)(&Al[(w * 32 + 16 + ln) * AL_S + kk * 32 + q * 8]);
#pragma unroll
      for (int nt = 0; nt < 8; ++nt) {
        bf16x8 a = *(const bf16x8*)(&WTl[(nt * 16 + ln) * WT_S + hh * 64 + kk * 32 + q * 8]);
        acc[0][nt] = __builtin_amdgcn_mfma_f32_16x16x32_bf16(a, b0, acc[0][nt], 0, 0, 0);
        acc[1][nt] = __builtin_amdgcn_mfma_f32_16x16x32_bf16(a, b1, acc[1][nt], 0, 0, 0);
      }
    }
  }
  // epilogue: lane holds D for m = m0b + w*32 + mt*16 + ln, n = nt*16 + q*4 + reg
  // m == NN is the zero row used by k_agg's pad slots (acc==0 there since Al was zeroed).
#pragma unroll
  for (int mt = 0; mt < 2; ++mt) {
    int m = m0b + w * 32 + mt * 16 + ln;
    if (m <= NN) {
      float sc = (m < NN) ? isd[r * NN + m] : 0.f;
      uint* yp = Yr + (size_t)m * 32;
#pragma unroll
      for (int nt = 0; nt < 8; ++nt) {
        f32x4 v = acc[mt][nt];
        uint u = __builtin_amdgcn_cvt_pk_fp8_f32(v[0] * sc, v[1] * sc, 0u, false);
        u = __builtin_amdgcn_cvt_pk_fp8_f32(v[2] * sc, v[3] * sc, u, true);
        yp[nt * 4 + q] = u;
      }
    }
  }
}

// ---------------- aggregation: channel-sliced (4 x 32ch), L2-resident table ----------------
// slice = blockIdx.x & 3 -> under round-robin blockIdx->XCD dispatch, each XCD touches
// only its 3.2 MB table slice (100k rows x 32 B) => gathers are L2 hits.
// Wave layout: lane = sub(2 nodes)*32 + slot(16)*2 + half(2); each lane loads the
// uint4 half of its slot's 32-B row slice. Depth-2 data prefetch, clamped indices.
__global__ __launch_bounds__(256, 8) void k_agg(const char* __restrict__ xw,
                                                const int* __restrict__ rps,
                                                const int* __restrict__ rpc,
                                                const int* __restrict__ ci,
                                                const float* __restrict__ isd,
                                                const float* __restrict__ bias,
                                                uint* __restrict__ hout, int relu_flag) {
  const int w = threadIdx.x >> 6;
  const int lane = threadIdx.x & 63;
  const int sub = lane >> 5;           // node within the wave's pair
  const int slot = (lane >> 1) & 15;   // edge slot (0..15)
  const int half = lane & 1;           // which 16-B half of the 32-ch slice
  const int slice = blockIdx.x & 3;    // channel slice (32 ch)
  const int grp = blockIdx.x >> 2;     // node group (8 nodes per block)
  const int node = grp * 8 + w * 2 + sub;   // < 50176
  const int nsafe = (node < NN) ? node : 0;

  const int meta = rpc[node];
  const int ng = meta & 0xffff;                 // steps of 16 slots
  const int end0 = (meta >> 16) & 0xffff;       // r0/r1 boundary slot
  const int lim = ng << 4;
  const int* ce = ci + rps[node];
  const float di0 = isd[nsafe];
  const float di1 = isd[NN + nsafe];
  const char* xs = xw + (size_t)slice * 32 + (size_t)half * 16;

  // wave-uniform step count = max over the two nodes
  int ot = __shfl_xor(ng, 32);
  const int mng = (ng > ot) ? ng : ot;

  // pipeline fill (depth-2): clamp OOB index positions to the zero row
  int pos = slot;
  int tl = ce[pos];
  int s0 = (pos < lim) ? tl : NN;
  uint4 d0 = *(const uint4*)(xs + ((size_t)(uint)s0 << 7));
  pos += 16;

  f32x2 acc[8];
#pragma unroll
  for (int j = 0; j < 8; ++j) { acc[j][0] = 0.f; acc[j][1] = 0.f; }

  int spos = slot;
  for (int q = 0; q < mng; ++q) {
    int tn = ce[pos];
    int s1 = (pos < lim) ? tn : NN;
    pos += 16;
    uint4 d1 = *(const uint4*)(xs + ((size_t)(uint)s1 << 7));  // prefetch next step
    const float sc = (spos < end0) ? di0 : di1;
    spos += 16;
    f32x2 sc2; sc2[0] = sc; sc2[1] = sc;
    f32x2 v;
    v = __builtin_amdgcn_cvt_pk_f32_fp8(d0.x, false); acc[0] += v * sc2;
    v = __builtin_amdgcn_cvt_pk_f32_fp8(d0.x, true);  acc[1] += v * sc2;
    v = __builtin_amdgcn_cvt_pk_f32_fp8(d0.y, false); acc[2] += v * sc2;
    v = __builtin_amdgcn_cvt_pk_f32_fp8(d0.y, true);  acc[3] += v * sc2;
    v = __builtin_amdgcn_cvt_pk_f32_fp8(d0.z, false); acc[4] += v * sc2;
    v = __builtin_amdgcn_cvt_pk_f32_fp8(d0.z, true);  acc[5] += v * sc2;
    v = __builtin_amdgcn_cvt_pk_f32_fp8(d0.w, false); acc[6] += v * sc2;
    v = __builtin_amdgcn_cvt_pk_f32_fp8(d0.w, true);  acc[7] += v * sc2;
    d0 = d1;
  }

  // reduce over the 16 slots (lane bits 1..4); halves/subs stay independent
#pragma unroll
  for (int mask = 2; mask <= 16; mask <<= 1) {
#pragma unroll
    for (int j = 0; j < 8; ++j) {
      f32x2 o;
      o[0] = __shfl_xor(acc[j][0], mask);
      o[1] = __shfl_xor(acc[j][1], mask);
      acc[j] += o;
    }
  }

  // lanes {0,1,32,33}: write this node's 16 channels [slice*32 + half*16, +16)
  if ((lane & 30) == 0 && node < NN) {
    const int ch0 = slice * 32 + half * 16;
    const float4* p0 = (const float4*)(bias + ch0);
    const float4* p1 = (const float4*)(bias + DD + ch0);
    float o[16];
#pragma unroll
    for (int j = 0; j < 4; ++j) {
      float4 a = p0[j], bq = p1[j];
      o[4 * j + 0] = acc[2 * j][0] + a.x + bq.x;
      o[4 * j + 1] = acc[2 * j][1] + a.y + bq.y;
      o[4 * j + 2] = acc[2 * j + 1][0] + a.z + bq.z;
      o[4 * j + 3] = acc[2 * j + 1][1] + a.w + bq.w;
    }
    if (relu_flag) {
#pragma unroll
      for (int j = 0; j < 16; ++j) o[j] = fmaxf(o[j], 0.f);
    }
    uint pk[8];
#pragma unroll
    for (int j = 0; j < 8; ++j)
      pk[j] = (uint)f2b(o[2 * j]) | ((uint)f2b(o[2 * j + 1]) << 16);
    uint4* dst = (uint4*)(hout + (size_t)node * 64 + slice * 16 + half * 8);
    dst[0] = make_uint4(pk[0], pk[1], pk[2], pk[3]);
    dst[1] = make_uint4(pk[4], pk[5], pk[6], pk[7]);
  }
}

// ---------------- pooling (batch ids sorted), packed bf16 input ----------------
#define PCHUNK 32
__global__ __launch_bounds__(64) void k_pool(const uint* __restrict__ h,
                                             const int* __restrict__ batch,
                                             float* __restrict__ sums,
                                             int* __restrict__ counts) {
  int lane = threadIdx.x;
  int n0 = blockIdx.x * PCHUNK;
  int n1 = n0 + PCHUNK;
  if (n1 > NN) n1 = NN;
  if (n0 >= NN) return;
  float aLo = 0.f, aHi = 0.f;
  int cnt = 0;
  int g = batch[n0];
  uint u = h[(size_t)n0 * 64 + lane];
  for (int n = n0; n < n1; ++n) {
    uint unext = 0;
    int gnext = g;
    if (n + 1 < n1) {
      unext = h[(size_t)(n + 1) * 64 + lane];
      gnext = batch[n + 1];
    }
    aLo += blo(u);
    aHi += bhi(u);
    cnt++;
    if (n + 1 < n1 && gnext != g) {
      atomicAdd(&sums[g * DD + lane * 2], aLo);
      atomicAdd(&sums[g * DD + lane * 2 + 1], aHi);
      if (lane == 0) atomicAdd(&counts[g], cnt);
      aLo = 0.f; aHi = 0.f; cnt = 0;
      g = gnext;
    }
    u = unext;
  }
  atomicAdd(&sums[g * DD + lane * 2], aLo);
  atomicAdd(&sums[g * DD + lane * 2 + 1], aHi);
  if (lane == 0) atomicAdd(&counts[g], cnt);
}

__global__ __launch_bounds__(512) void k_final(const float* __restrict__ sums,
                                               const int* __restrict__ counts,
                                               const float* __restrict__ lin_w,
                                               const float* __restrict__ lin_b,
                                               float* __restrict__ out) {
  int t = threadIdx.x;  // 512 = 64 graphs x 8 classes
  int g = t >> 3, co = t & 7;
  float cnt = (float)counts[g];
  if (cnt < 1.f) cnt = 1.f;
  float inv = 1.f / cnt;
  float v = lin_b[co];
  for (int d = 0; d < DD; ++d) v += (sums[g * DD + d] * inv) * lin_w[d * CCLS + co];
  out[t] = v;
}

extern "C" void kernel_launch(void* const* d_in, const int* in_sizes, int n_in,
                              void* d_out, int out_size, void* d_ws, size_t ws_size,
                              hipStream_t stream) {
  (void)in_sizes; (void)n_in; (void)out_size; (void)ws_size;
  const float* x     = (const float*)d_in[0];
  const float* W     = (const float*)d_in[1];
  const float* b     = (const float*)d_in[2];
  const float* lin_w = (const float*)d_in[3];
  const float* lin_b = (const float*)d_in[4];
  const int*   EI    = (const int*)d_in[5];
  const int*   batch = (const int*)d_in[6];
  float* out = (float*)d_out;

  char* ws = (char*)d_ws;
  uint*   h1    = (uint*)(ws + OFF_H1);       // bf16 packed
  ushort* WbfT  = (ushort*)(ws + OFF_WBT);
  float*  isd   = (float*)(ws + OFF_ISD);
  int*    rps   = (int*)(ws + OFF_RP);
  int*    rpc   = rps + NBUK * 256;
  int*    ci    = (int*)(ws + OFF_CI);
  uint*   bdata = (uint*)(ws + OFF_BD);
  uint*   xw    = (uint*)(ws + OFF_XW);       // fp8 table (isd-prescaled), aliases bdata
  char*   zb    = ws + OFF_ZERO;
  int*    gcur  = (int*)(zb + ZO_GCUR);
  float*  sums  = (float*)(zb + ZO_SUM);
  int*    counts= (int*)(zb + ZO_CNT);

  (void)hipMemsetAsync(zb, 0, ZERO_BYTES, stream);

  k_wprep<<<256, 256, 0, stream>>>(W, WbfT);
  k_part<<<dim3((EE + 4095) / 4096, RR), 256, 0, stream>>>(EI, gcur, bdata);
  k_csr<<<NBUK, 256, 0, stream>>>(bdata, gcur, isd, rps, rpc, ci);

  for (int l = 0; l < LL; ++l) {
    const ushort* WTl_g = WbfT + (size_t)l * RR * DD * DD;
    if (l == 0)
      k_gemm<0><<<dim3((NN + 127) / 128, RR), 256, 0, stream>>>((const void*)x, WTl_g, isd, xw);
    else
      k_gemm<1><<<dim3((NN + 127) / 128, RR), 256, 0, stream>>>((const void*)h1, WTl_g, isd, xw);
    // 4 slices x (50176/8) node-groups
    k_agg<<<4 * (NBUK * 256 / 8), 256, 0, stream>>>((const char*)xw, rps, rpc, ci, isd,
                                                    b + (size_t)l * RR * DD, h1,
                                                    (l < LL - 1) ? 1 : 0);
  }
  k_pool<<<(NN + PCHUNK - 1) / PCHUNK, 64, 0, stream>>>(h1, batch, sums, counts);
  k_final<<<1, GG * CCLS, 0, stream>>>(sums, counts, lin_w, lin_b, out);
}

// Round 6
// 297.512 us; speedup vs baseline: 1.2380x; 1.2380x over previous
//
#include <hip/hip_runtime.h>
#include <math.h>

#define NN 50000
#define EE 800000
#define RR 2
#define LL 2
#define DD 128
#define GG 64
#define CCLS 8
#define NBUK 196     // buckets of 256 dst nodes: bucket = dst >> 8
#define BCAP 4608    // max raw edges per bucket per relation (mean 4082, sigma 64; +8 sigma)
#define BCI  12000   // per-bucket CSR slots (r0,r1 each padded to %8 per node, +32 tail)
                     // mean 10468, sigma ~104 -> +8 sigma ~11.3k < 12000-32

typedef unsigned int uint;
typedef unsigned short ushort;
typedef short bf16x8 __attribute__((ext_vector_type(8)));
typedef float f32x4 __attribute__((ext_vector_type(4)));
typedef float f32x2 __attribute__((ext_vector_type(2)));

// ---------------- workspace layout (bytes), total 42,575,936 ----------------
#define OFF_AGG   ((size_t)0)            // agg [N][256] bf16             25,600,000
                                         //  (bdata [2][196][BCAP] uint 7,225,344 ALIASES
                                         //   this region; dead after k_csr2.
                                         //   gemm-l1 packs h into agg rows in place.)
#define OFF_WBT   ((size_t)25600000)     // Ws [L][128 n][256 k] bf16        131,072
#define OFF_ISD   ((size_t)25731072)     // [2][N] f32                       400,000
#define OFF_RP    ((size_t)26131072)     // rps/rpc/degs [50176] i32 each    602,112
#define OFF_CI    ((size_t)26733184)     // [196][BCI] i32                 9,408,000
#define OFF_ZERO  ((size_t)36141184)     // 34,624
#define OFF_T     ((size_t)36175808)     // fp8 table [N+1][128]           6,400,128
// zero region internal offsets (bytes)
#define ZO_GCUR 0        // [2][196] i32 bucket counters (1568 B, pad 1600)
#define ZO_SUM  1600     // [G][D] f32 (32768 B)
#define ZO_CNT  34368    // [G] i32 (256 B)
#define ZERO_BYTES 34624

static __device__ __forceinline__ ushort f2b(float f) {
  uint u = __float_as_uint(f);
  uint r = (u + 0x7fffu + ((u >> 16) & 1u)) >> 16;
  return (ushort)r;
}
static __device__ __forceinline__ float blo(uint u) { return __uint_as_float(u << 16); }
static __device__ __forceinline__ float bhi(uint u) { return __uint_as_float(u & 0xffff0000u); }

// ---------------- W prep: fp32 W[l][r][k][n] -> bf16 Ws[l][n][r*128+k] (stacked-K) ----------------
__global__ __launch_bounds__(256) void k_wprep(const float* __restrict__ W,
                                               ushort* __restrict__ WT) {
  int idx = blockIdx.x * 256 + threadIdx.x;  // 65536 total
  int lr = idx >> 14;
  int l = lr >> 1, r = lr & 1;
  int rem = idx & 16383;
  int n = rem >> 7, k = rem & 127;
  WT[l * 32768 + n * 256 + r * 128 + k] = f2b(W[lr * 16384 + k * 128 + n]);
}

// ---------------- x -> fp8 table T[N+1][128] (unscaled; row NN = zero) ----------------
__global__ __launch_bounds__(256) void k_xq(const float* __restrict__ x,
                                            uint* __restrict__ T) {
  int idx = blockIdx.x * 256 + threadIdx.x;  // (NN+1)*32 = 1,600,032 uints
  if (idx >= (NN + 1) * 32) return;
  int row = idx >> 5, q = idx & 31;
  uint u = 0;
  if (row < NN) {
    float4 a = ((const float4*)x)[(size_t)row * 32 + q];
    u = __builtin_amdgcn_cvt_pk_fp8_f32(a.x, a.y, 0u, false);
    u = __builtin_amdgcn_cvt_pk_fp8_f32(a.z, a.w, u, true);
  }
  T[idx] = u;
}

// ---------------- phase 1: partition edges into dst buckets (coalesced) ----------------
__global__ __launch_bounds__(256) void k_part(const int* __restrict__ EI,
                                              int* __restrict__ gcur,
                                              uint* __restrict__ bdata) {
  __shared__ int hist[256];
  __shared__ int sbase[256];
  __shared__ int gbase[256];
  __shared__ int lcur[256];
  __shared__ uint stage[4096];
  __shared__ unsigned char bstage[4096];
  const int r = blockIdx.y;
  const int t = threadIdx.x;
  const int e0 = blockIdx.x * 4096;
  const int cnt = min(4096, EE - e0);
  hist[t] = 0;
  lcur[t] = 0;
  __syncthreads();

  int src[16], dst[16];
  bool val[4];
#pragma unroll
  for (int j = 0; j < 4; ++j) {
    int i4 = (j * 256 + t) * 4;
    val[j] = (i4 < cnt);
    if (val[j]) {
      int4 s4 = *(const int4*)(EI + (size_t)r * 2 * EE + e0 + i4);
      int4 d4 = *(const int4*)(EI + (size_t)r * 2 * EE + EE + e0 + i4);
      src[j * 4 + 0] = s4.x; src[j * 4 + 1] = s4.y; src[j * 4 + 2] = s4.z; src[j * 4 + 3] = s4.w;
      dst[j * 4 + 0] = d4.x; dst[j * 4 + 1] = d4.y; dst[j * 4 + 2] = d4.z; dst[j * 4 + 3] = d4.w;
#pragma unroll
      for (int i = 0; i < 4; ++i) atomicAdd(&hist[dst[j * 4 + i] >> 8], 1);
    }
  }
  __syncthreads();
  int hv = hist[t];
  if (t < NBUK && hv > 0)
    gbase[t] = atomicAdd(&gcur[r * NBUK + t], hv);
  else
    gbase[t] = 0;
  sbase[t] = hv;
  __syncthreads();
  for (int off = 1; off < 256; off <<= 1) {
    int u = (t >= off) ? sbase[t - off] : 0;
    __syncthreads();
    sbase[t] += u;
    __syncthreads();
  }
  int incl = sbase[t];
  hist[t] = incl - hv;
  __syncthreads();
#pragma unroll
  for (int j = 0; j < 4; ++j) {
    if (val[j]) {
#pragma unroll
      for (int i = 0; i < 4; ++i) {
        int d = dst[j * 4 + i];
        int b = d >> 8;
        int p = atomicAdd(&lcur[b], 1);
        int pos = hist[b] + p;
        stage[pos] = ((uint)src[j * 4 + i] << 8) | (uint)(d & 255);
        bstage[pos] = (unsigned char)b;
      }
    }
  }
  __syncthreads();
  for (int s = t; s < cnt; s += 256) {
    int b = (int)bstage[s];
    bdata[(size_t)(r * NBUK + b) * BCAP + gbase[b] + (s - hist[b])] = stage[s];
  }
}

// ---------------- phase 2a: degrees -> isd, rps, rpc, degs ----------------
// Per node: segment = [r0: deg0 edges + self, pad->%8][r1: deg1 edges + self, pad->%8].
__global__ __launch_bounds__(256) void k_csr1(const uint* __restrict__ bdata,
                                              const int* __restrict__ gcur,
                                              float* __restrict__ isd,
                                              int* __restrict__ rps,
                                              int* __restrict__ rpc,
                                              int* __restrict__ degs) {
  __shared__ int lcnt0[256], lcnt1[256], lrp[256];
  const int b = blockIdx.x;
  const int t = threadIdx.x;
  const int cnt0 = gcur[b];
  const int cnt1 = gcur[NBUK + b];
  const uint* bd0 = bdata + (size_t)b * BCAP;
  const uint* bd1 = bdata + (size_t)(NBUK + b) * BCAP;
  lcnt0[t] = 0; lcnt1[t] = 0;
  __syncthreads();
  for (int s = t; s < cnt0; s += 256) atomicAdd(&lcnt0[bd0[s] & 255u], 1);
  for (int s = t; s < cnt1; s += 256) atomicAdd(&lcnt1[bd1[s] & 255u], 1);
  __syncthreads();
  const int deg0 = lcnt0[t];
  const int deg1 = lcnt1[t];
  const int node = b * 256 + t;
  const int valid = (node < NN) ? 1 : 0;
  const int ng0 = valid ? ((deg0 + 8) >> 3) : 0;   // ceil((deg0+1)/8)
  const int ng1 = valid ? ((deg1 + 8) >> 3) : 0;
  const int sz = (ng0 + ng1) << 3;
  lrp[t] = sz;
  __syncthreads();
  for (int off = 1; off < 256; off <<= 1) {
    int u = (t >= off) ? lrp[t - off] : 0;
    __syncthreads();
    lrp[t] += u;
    __syncthreads();
  }
  const int ex = lrp[t] - sz;
  rps[node] = b * BCI + ex;
  rpc[node] = ng0 | (ng1 << 16);
  degs[node] = deg0 | (deg1 << 16);
  if (valid) {
    isd[node] = rsqrtf((float)(deg0 + 1));
    isd[NN + node] = rsqrtf((float)(deg1 + 1));
  }
}

// ---------------- phase 2b: scatter edges -> ci entries (src16 | bf16(isd_r[src])<<16) ----------------
__global__ __launch_bounds__(256) void k_csr2(const uint* __restrict__ bdata,
                                              const int* __restrict__ gcur,
                                              const float* __restrict__ isd,
                                              const int* __restrict__ rps,
                                              const int* __restrict__ rpc,
                                              const int* __restrict__ degs,
                                              int* __restrict__ ci) {
  __shared__ int lex[256], lb1[256], lcurA[256], lcurB[256];
  __shared__ int cstage[BCI];   // 48,000 B + 4 KB = 52 KB
  __shared__ int shtot;
  const int b = blockIdx.x;
  const int t = threadIdx.x;
  const int node = b * 256 + t;
  const int cnt0 = gcur[b];
  const int cnt1 = gcur[NBUK + b];
  const uint* bd0 = bdata + (size_t)b * BCAP;
  const uint* bd1 = bdata + (size_t)(NBUK + b) * BCAP;
  const int ex = rps[node] - b * BCI;
  const int meta = rpc[node];
  const int ng0 = meta & 0xffff, ng1 = (meta >> 16) & 0xffff;
  const int dg = degs[node];
  const int deg0 = dg & 0xffff, deg1 = (dg >> 16) & 0xffff;
  lex[t] = ex;
  lb1[t] = ng0 << 3;
  lcurA[t] = 0;
  lcurB[t] = 0;
  if (t == 255) shtot = ex + ((ng0 + ng1) << 3);
  __syncthreads();
  const int tot = shtot;
  if (t < 32) cstage[tot + t] = NN;   // tail pads (scale bits 0) for k_agg over-read
  if (node < NN) {
    // selfs + pads
    cstage[ex + deg0] = node | ((uint)f2b(isd[node]) << 16);
    for (int p = deg0 + 1; p < (ng0 << 3); ++p) cstage[ex + p] = NN;
    const int e1 = ex + (ng0 << 3);
    cstage[e1 + deg1] = node | ((uint)f2b(isd[NN + node]) << 16);
    for (int p = deg1 + 1; p < (ng1 << 3); ++p) cstage[e1 + p] = NN;
  }
  // scatter real edges (disjoint slots vs selfs/pads)
  for (int s = t; s < cnt0; s += 256) {
    uint pr = bd0[s];
    int j = (int)(pr & 255u);
    int sr = (int)(pr >> 8);
    int p = atomicAdd(&lcurA[j], 1);
    cstage[lex[j] + p] = sr | ((uint)f2b(isd[sr]) << 16);
  }
  for (int s = t; s < cnt1; s += 256) {
    uint pr = bd1[s];
    int j = (int)(pr & 255u);
    int sr = (int)(pr >> 8);
    int p = atomicAdd(&lcurB[j], 1);
    cstage[lex[j] + lb1[j] + p] = sr | ((uint)f2b(isd[NN + sr]) << 16);
  }
  __syncthreads();
  int* co = ci + (size_t)b * BCI;
  const int on = tot + 32;
  for (int s = t; s < on; s += 256) co[s] = cstage[s];
}

// ---------------- aggregation: gather fp8 T rows, per-edge bf16 scale, dual accumulators ----------------
// lane = g*8 + c: g = edge slot (0..7), c = channel-quad (16 fp8 ch = 1 uint4).
// One pipeline spans the r0 sub-loop then r1 sub-loop (segments adjacent); prefetch
// indices clamped to the zero row NN. Output: agg[node][0..127]=di0*sum0, [128..255]=di1*sum1 (bf16).
#define AGG_STEP(A)                                                            \
  {                                                                            \
    uint e2 = (uint)ce[ip];                                                    \
    int s2 = (ip < lim) ? (int)(e2 & 0xffffu) : NN;                            \
    float f2 = bhi(e2);                                                        \
    ip += 8;                                                                   \
    uint4 d2 = *(const uint4*)(Tb + ((((size_t)(uint)s2) << 7) + cb));         \
    f32x2 sc; sc[0] = f0; sc[1] = f0;                                          \
    f32x2 v;                                                                   \
    v = __builtin_amdgcn_cvt_pk_f32_fp8(d0.x, false); A[0] += v * sc;          \
    v = __builtin_amdgcn_cvt_pk_f32_fp8(d0.x, true);  A[1] += v * sc;          \
    v = __builtin_amdgcn_cvt_pk_f32_fp8(d0.y, false); A[2] += v * sc;          \
    v = __builtin_amdgcn_cvt_pk_f32_fp8(d0.y, true);  A[3] += v * sc;          \
    v = __builtin_amdgcn_cvt_pk_f32_fp8(d0.z, false); A[4] += v * sc;          \
    v = __builtin_amdgcn_cvt_pk_f32_fp8(d0.z, true);  A[5] += v * sc;          \
    v = __builtin_amdgcn_cvt_pk_f32_fp8(d0.w, false); A[6] += v * sc;          \
    v = __builtin_amdgcn_cvt_pk_f32_fp8(d0.w, true);  A[7] += v * sc;          \
    d0 = d1; d1 = d2; f0 = f1; f1 = f2;                                        \
  }

__global__ __launch_bounds__(256, 6) void k_agg(const char* __restrict__ Tb,
                                                const int* __restrict__ rps,
                                                const int* __restrict__ rpc,
                                                const int* __restrict__ ci,
                                                const float* __restrict__ isd,
                                                ushort* __restrict__ aggo) {
  const int w = threadIdx.x >> 6;
  const int lane = threadIdx.x & 63;
  const int g = lane >> 3, c = lane & 7;
  const int node = blockIdx.x * 4 + w;   // 0..50175
  const size_t cb = (size_t)c * 16;

  const int meta = rpc[node];
  const int ng0 = meta & 0xffff;
  const int ng1 = (meta >> 16) & 0xffff;
  const int lim = (ng0 + ng1) << 3;
  const int* ce = ci + rps[node];
  const int nsafe = (node < NN) ? node : 0;
  const float di0 = isd[nsafe];
  const float di1 = isd[NN + nsafe];

  // pipeline fill: depth-2 data, scales carried alongside
  int ip = g;
  uint e0 = (uint)ce[ip];
  int s0 = (ip < lim) ? (int)(e0 & 0xffffu) : NN;
  float f0 = bhi(e0);
  ip += 8;
  uint4 d0 = *(const uint4*)(Tb + ((((size_t)(uint)s0) << 7) + cb));
  uint e1 = (uint)ce[ip];
  int s1 = (ip < lim) ? (int)(e1 & 0xffffu) : NN;
  float f1 = bhi(e1);
  ip += 8;
  uint4 d1 = *(const uint4*)(Tb + ((((size_t)(uint)s1) << 7) + cb));

  f32x2 a0[8], a1[8];
#pragma unroll
  for (int j = 0; j < 8; ++j) { a0[j][0] = 0.f; a0[j][1] = 0.f; a1[j][0] = 0.f; a1[j][1] = 0.f; }

  for (int q = 0; q < ng0; ++q) AGG_STEP(a0);
  for (int q = 0; q < ng1; ++q) AGG_STEP(a1);

  // reduce over 8 edge slots (lane bits 3,4,5)
#pragma unroll
  for (int mask = 8; mask <= 32; mask <<= 1) {
#pragma unroll
    for (int j = 0; j < 8; ++j) {
      f32x2 o, p;
      o[0] = __shfl_xor(a0[j][0], mask);
      o[1] = __shfl_xor(a0[j][1], mask);
      p[0] = __shfl_xor(a1[j][0], mask);
      p[1] = __shfl_xor(a1[j][1], mask);
      a0[j] += o;
      a1[j] += p;
    }
  }

  if (g == 0 && node < NN) {   // lanes 0..7: write 16 ch per relation
    ushort* row = aggo + (size_t)node * 256;
    uint pk[8];
#pragma unroll
    for (int j = 0; j < 4; ++j) {
      pk[2 * j] = (uint)f2b(a0[2 * j][0] * di0) | ((uint)f2b(a0[2 * j][1] * di0) << 16);
      pk[2 * j + 1] = (uint)f2b(a0[2 * j + 1][0] * di0) | ((uint)f2b(a0[2 * j + 1][1] * di0) << 16);
    }
    *(uint4*)(row + c * 16) = make_uint4(pk[0], pk[1], pk[2], pk[3]);
    *(uint4*)(row + c * 16 + 8) = make_uint4(pk[4], pk[5], pk[6], pk[7]);
#pragma unroll
    for (int j = 0; j < 4; ++j) {
      pk[2 * j] = (uint)f2b(a1[2 * j][0] * di1) | ((uint)f2b(a1[2 * j][1] * di1) << 16);
      pk[2 * j + 1] = (uint)f2b(a1[2 * j + 1][0] * di1) | ((uint)f2b(a1[2 * j + 1][1] * di1) << 16);
    }
    *(uint4*)(row + 128 + c * 16) = make_uint4(pk[0], pk[1], pk[2], pk[3]);
    *(uint4*)(row + 128 + c * 16 + 8) = make_uint4(pk[4], pk[5], pk[6], pk[7]);
  }
}

// ---------------- MFMA GEMM: out[m][:] = agg[m][0:256] @ Ws[l] + bsum, K=256, BM=64 ----------------
// OUT=0: layer-0 -> relu -> fp8 into T (incl. zero row NN). OUT=1: layer-1 -> packed
// bf16 IN PLACE into agg rows (stride 256 ush; first 64 uints of each row).
#define AL_S 72
#define WT_S 72
template <int OUT>
__global__ __launch_bounds__(256) void k_gemm(const ushort* __restrict__ A,
                                              const ushort* __restrict__ WTg,
                                              const float* __restrict__ bias,
                                              uint* __restrict__ Yfp8,
                                              ushort* __restrict__ Ybf) {
  __shared__ ushort WTl[128 * WT_S];
  __shared__ ushort Al[64 * AL_S];
  const int m0b = blockIdx.x * 64;
  const int t = threadIdx.x;
  const int w = t >> 6, L = t & 63, q = L >> 4, ln = L & 15;

  f32x4 acc[8];
#pragma unroll
  for (int nt = 0; nt < 8; ++nt) {
    acc[nt][0] = 0.f; acc[nt][1] = 0.f; acc[nt][2] = 0.f; acc[nt][3] = 0.f;
  }

  for (int hh = 0; hh < 4; ++hh) {
    __syncthreads();
    {
      // stage WT half: 128 n x 64 k
      int n = t >> 1, half = t & 1;
#pragma unroll
      for (int j = 0; j < 4; ++j)
        *(uint4*)(&WTl[n * WT_S + half * 32 + j * 8]) =
            *(const uint4*)(WTg + n * 256 + hh * 64 + half * 32 + j * 8);
      // stage A half: 64 m x 64 k
      int row = t >> 2, seg = t & 3;
      int gm = m0b + row;
      if (gm < NN) {
#pragma unroll
        for (int j = 0; j < 2; ++j)
          *(uint4*)(&Al[row * AL_S + seg * 16 + j * 8]) =
              *(const uint4*)(A + (size_t)gm * 256 + hh * 64 + seg * 16 + j * 8);
      } else {
        uint4 z = make_uint4(0, 0, 0, 0);
#pragma unroll
        for (int j = 0; j < 2; ++j) *(uint4*)(&Al[row * AL_S + seg * 16 + j * 8]) = z;
      }
    }
    __syncthreads();
#pragma unroll
    for (int kk = 0; kk < 2; ++kk) {
      bf16x8 bfr = *(const bf16x8*)(&Al[(w * 16 + ln) * AL_S + kk * 32 + q * 8]);
#pragma unroll
      for (int nt = 0; nt < 8; ++nt) {
        bf16x8 a = *(const bf16x8*)(&WTl[(nt * 16 + ln) * WT_S + kk * 32 + q * 8]);
        acc[nt] = __builtin_amdgcn_mfma_f32_16x16x32_bf16(a, bfr, acc[nt], 0, 0, 0);
      }
    }
  }
  // epilogue: m = m0b + w*16 + ln; n = nt*16 + q*4 + reg
  const int m = m0b + w * 16 + ln;
  if (OUT == 0) {
    if (m < NN) {
      uint* yp = Yfp8 + (size_t)m * 32;
#pragma unroll
      for (int nt = 0; nt < 8; ++nt) {
        int n0 = nt * 16 + q * 4;
        float4 bL = *(const float4*)(bias + n0);
        float4 bH = *(const float4*)(bias + 128 + n0);
        f32x4 v = acc[nt];
        float o0 = fmaxf(v[0] + bL.x + bH.x, 0.f);
        float o1 = fmaxf(v[1] + bL.y + bH.y, 0.f);
        float o2 = fmaxf(v[2] + bL.z + bH.z, 0.f);
        float o3 = fmaxf(v[3] + bL.w + bH.w, 0.f);
        uint u = __builtin_amdgcn_cvt_pk_fp8_f32(o0, o1, 0u, false);
        u = __builtin_amdgcn_cvt_pk_fp8_f32(o2, o3, u, true);
        yp[nt * 4 + q] = u;
      }
    } else if (m == NN) {
      uint* yp = Yfp8 + (size_t)m * 32;
#pragma unroll
      for (int nt = 0; nt < 8; ++nt) yp[nt * 4 + q] = 0u;
    }
  } else {
    if (m < NN) {
      uint* yp = (uint*)(Ybf + (size_t)m * 256);
#pragma unroll
      for (int nt = 0; nt < 8; ++nt) {
        int n0 = nt * 16 + q * 4;
        float4 bL = *(const float4*)(bias + n0);
        float4 bH = *(const float4*)(bias + 128 + n0);
        f32x4 v = acc[nt];
        float o0 = v[0] + bL.x + bH.x;
        float o1 = v[1] + bL.y + bH.y;
        float o2 = v[2] + bL.z + bH.z;
        float o3 = v[3] + bL.w + bH.w;
        yp[nt * 8 + q * 2] = (uint)f2b(o0) | ((uint)f2b(o1) << 16);
        yp[nt * 8 + q * 2 + 1] = (uint)f2b(o2) | ((uint)f2b(o3) << 16);
      }
    }
  }
}

// ---------------- pooling (batch ids sorted); h packed bf16 in agg rows, stride 128 uints ----------------
#define PCHUNK 32
__global__ __launch_bounds__(64) void k_pool(const uint* __restrict__ h,
                                             const int* __restrict__ batch,
                                             float* __restrict__ sums,
                                             int* __restrict__ counts) {
  int lane = threadIdx.x;
  int n0 = blockIdx.x * PCHUNK;
  int n1 = n0 + PCHUNK;
  if (n1 > NN) n1 = NN;
  if (n0 >= NN) return;
  float aLo = 0.f, aHi = 0.f;
  int cnt = 0;
  int g = batch[n0];
  uint u = h[(size_t)n0 * 128 + lane];
  for (int n = n0; n < n1; ++n) {
    uint unext = 0;
    int gnext = g;
    if (n + 1 < n1) {
      unext = h[(size_t)(n + 1) * 128 + lane];
      gnext = batch[n + 1];
    }
    aLo += blo(u);
    aHi += bhi(u);
    cnt++;
    if (n + 1 < n1 && gnext != g) {
      atomicAdd(&sums[g * DD + lane * 2], aLo);
      atomicAdd(&sums[g * DD + lane * 2 + 1], aHi);
      if (lane == 0) atomicAdd(&counts[g], cnt);
      aLo = 0.f; aHi = 0.f; cnt = 0;
      g = gnext;
    }
    u = unext;
  }
  atomicAdd(&sums[g * DD + lane * 2], aLo);
  atomicAdd(&sums[g * DD + lane * 2 + 1], aHi);
  if (lane == 0) atomicAdd(&counts[g], cnt);
}

__global__ __launch_bounds__(512) void k_final(const float* __restrict__ sums,
                                               const int* __restrict__ counts,
                                               const float* __restrict__ lin_w,
                                               const float* __restrict__ lin_b,
                                               float* __restrict__ out) {
  int t = threadIdx.x;  // 512 = 64 graphs x 8 classes
  int g = t >> 3, co = t & 7;
  float cnt = (float)counts[g];
  if (cnt < 1.f) cnt = 1.f;
  float inv = 1.f / cnt;
  float v = lin_b[co];
  for (int d = 0; d < DD; ++d) v += (sums[g * DD + d] * inv) * lin_w[d * CCLS + co];
  out[t] = v;
}

extern "C" void kernel_launch(void* const* d_in, const int* in_sizes, int n_in,
                              void* d_out, int out_size, void* d_ws, size_t ws_size,
                              hipStream_t stream) {
  (void)in_sizes; (void)n_in; (void)out_size; (void)ws_size;
  const float* x     = (const float*)d_in[0];
  const float* W     = (const float*)d_in[1];
  const float* b     = (const float*)d_in[2];
  const float* lin_w = (const float*)d_in[3];
  const float* lin_b = (const float*)d_in[4];
  const int*   EI    = (const int*)d_in[5];
  const int*   batch = (const int*)d_in[6];
  float* out = (float*)d_out;

  char* ws = (char*)d_ws;
  ushort* agg   = (ushort*)(ws + OFF_AGG);
  uint*   bdata = (uint*)(ws + OFF_AGG);      // ALIAS: dead after k_csr2
  ushort* Ws    = (ushort*)(ws + OFF_WBT);
  float*  isd   = (float*)(ws + OFF_ISD);
  int*    rps   = (int*)(ws + OFF_RP);
  int*    rpc   = rps + NBUK * 256;
  int*    degs  = rpc + NBUK * 256;
  int*    ci    = (int*)(ws + OFF_CI);
  uint*   T     = (uint*)(ws + OFF_T);
  char*   zb    = ws + OFF_ZERO;
  int*    gcur  = (int*)(zb + ZO_GCUR);
  float*  sums  = (float*)(zb + ZO_SUM);
  int*    counts= (int*)(zb + ZO_CNT);

  (void)hipMemsetAsync(zb, 0, ZERO_BYTES, stream);

  k_wprep<<<256, 256, 0, stream>>>(W, Ws);
  k_xq<<<((NN + 1) * 32 + 255) / 256, 256, 0, stream>>>(x, T);
  k_part<<<dim3((EE + 4095) / 4096, RR), 256, 0, stream>>>(EI, gcur, bdata);
  k_csr1<<<NBUK, 256, 0, stream>>>(bdata, gcur, isd, rps, rpc, degs);
  k_csr2<<<NBUK, 256, 0, stream>>>(bdata, gcur, isd, rps, rpc, degs, ci);

  const int gagg = NBUK * 256 / 4;
  const int ggemm = (NN + 63) / 64;
  // layer 0: aggregate fp8(x), GEMM K=256 -> relu -> fp8 table T (in place over T0)
  k_agg<<<gagg, 256, 0, stream>>>((const char*)T, rps, rpc, ci, isd, agg);
  k_gemm<0><<<ggemm, 256, 0, stream>>>(agg, Ws, b, T, nullptr);
  // layer 1: aggregate T1, GEMM K=256 -> packed bf16 h in place in agg rows
  k_agg<<<gagg, 256, 0, stream>>>((const char*)T, rps, rpc, ci, isd, agg);
  k_gemm<1><<<ggemm, 256, 0, stream>>>(agg, Ws + 32768, b + 256, nullptr, agg);

  k_pool<<<(NN + PCHUNK - 1) / PCHUNK, 64, 0, stream>>>((const uint*)agg, batch, sums, counts);
  k_final<<<1, GG * CCLS, 0, stream>>>(sums, counts, lin_w, lin_b, out);
}